// Round 1
// baseline (1973.248 us; speedup 1.0000x reference)
//
#include <hip/hip_runtime.h>
#include <cstdint>
#include <cstddef>

#define NN 100000
#define NE 1600000
#define NEP (NE + NN)   // edges + self-loops = 1,700,000

__device__ __forceinline__ float elu_f(float x) {
    return x > 0.f ? x : __expf(x) - 1.f;
}

// ---------------- bio encoder: Linear(64,16) -> BN -> ELU -> Linear(16,16) -> ELU
// writes x[i*66 + 50 .. 66)
__global__ __launch_bounds__(256) void bio_kernel(
    const float* __restrict__ xb, const float* __restrict__ W1, const float* __restrict__ b1,
    const float* __restrict__ g0, const float* __restrict__ bb0,
    const float* __restrict__ m0, const float* __restrict__ v0,
    const float* __restrict__ W2, const float* __restrict__ b2,
    float* __restrict__ x)
{
    __shared__ float sW1[16*64], sW2[16*16], sb1[16], sb2[16], ss[16], st[16];
    int tid = threadIdx.x;
    for (int idx = tid; idx < 1024; idx += 256) sW1[idx] = W1[idx];
    if (tid < 256) sW2[tid] = W2[tid];
    if (tid < 16) {
        sb1[tid] = b1[tid]; sb2[tid] = b2[tid];
        float s = g0[tid] * rsqrtf(v0[tid] + 1e-5f);
        ss[tid] = s; st[tid] = bb0[tid] - m0[tid] * s;
    }
    __syncthreads();
    int i = blockIdx.x * 256 + tid;
    if (i >= NN) return;
    float bio[64];
    const float4* p = (const float4*)(xb + (size_t)i * 64);
    #pragma unroll
    for (int q = 0; q < 16; q++) {
        float4 f = p[q];
        bio[q*4] = f.x; bio[q*4+1] = f.y; bio[q*4+2] = f.z; bio[q*4+3] = f.w;
    }
    float t1[16];
    #pragma unroll
    for (int j = 0; j < 16; j++) {
        float acc = sb1[j];
        #pragma unroll
        for (int k = 0; k < 64; k++) acc += bio[k] * sW1[j*64 + k];
        acc = acc * ss[j] + st[j];
        t1[j] = elu_f(acc);
    }
    float* xo = x + (size_t)i * 66 + 50;
    #pragma unroll
    for (int j = 0; j < 16; j++) {
        float acc = sb2[j];
        #pragma unroll
        for (int k = 0; k < 16; k++) acc += t1[k] * sW2[j*16 + k];
        xo[j] = elu_f(acc);
    }
}

// copy x_pca into x[:, 0:50]
__global__ __launch_bounds__(256) void copy_pca(const float* __restrict__ xp, float* __restrict__ x)
{
    int t = blockIdx.x * 256 + threadIdx.x;
    if (t >= NN * 50) return;
    int i = t / 50, j = t - i * 50;
    x[(size_t)i * 66 + j] = xp[t];
}

// ---------------- row-tiled GEMM: out[n,DOUT] = in[n,DIN] @ W[DOUT,DIN]^T + b
// 256 threads, NPB nodes per block; requires 256 % DOUT == 0
template<int DIN, int DOUT, int NPB>
__global__ __launch_bounds__(256) void gemm_rowtile(
    const float* __restrict__ in, const float* __restrict__ W,
    const float* __restrict__ bias, float* __restrict__ out, int n)
{
    constexpr int GROUPS = 256 / DOUT;
    constexpr int RPT = NPB / GROUPS;
    __shared__ float sW[DOUT * DIN];
    __shared__ float sx[NPB * DIN];
    __shared__ float sb[DOUT];
    int tid = threadIdx.x;
    for (int idx = tid; idx < DOUT * DIN; idx += 256) sW[idx] = W[idx];
    if (tid < DOUT) sb[tid] = bias[tid];
    int node0 = blockIdx.x * NPB;
    for (int idx = tid; idx < NPB * DIN; idx += 256) {
        int r = idx / DIN, c = idx - r * DIN;
        int i = node0 + r;
        sx[idx] = (i < n) ? in[(size_t)i * DIN + c] : 0.f;
    }
    __syncthreads();
    int j = tid % DOUT;
    int g = tid / DOUT;
    float acc[RPT];
    #pragma unroll
    for (int r = 0; r < RPT; r++) acc[r] = sb[j];
    for (int k = 0; k < DIN; k++) {
        float w = sW[j * DIN + k];
        #pragma unroll
        for (int r = 0; r < RPT; r++) acc[r] += sx[(g * RPT + r) * DIN + k] * w;
    }
    #pragma unroll
    for (int r = 0; r < RPT; r++) {
        int i = node0 + g * RPT + r;
        if (i < n) out[(size_t)i * DOUT + j] = acc[r];
    }
}

// ---------------- layer-1 edge logits: one thread per (edge, head)
__global__ __launch_bounds__(256) void edge1(
    const int* __restrict__ ei, const float* __restrict__ xl, const float* __restrict__ xr,
    const float* __restrict__ att, float* __restrict__ expl, float* __restrict__ denom)
{
    __shared__ float satt[128];
    int tid = threadIdx.x;
    if (tid < 128) satt[tid] = att[tid];
    __syncthreads();
    int t = blockIdx.x * 256 + tid;
    if (t >= NEP * 4) return;
    int e = t >> 2, h = t & 3;
    int src, dst;
    if (e < NE) { src = ei[e]; dst = ei[NE + e]; } else { src = dst = e - NE; }
    const float4* pl = (const float4*)(xl + (size_t)src * 128 + h * 32);
    const float4* pr = (const float4*)(xr + (size_t)dst * 128 + h * 32);
    const float* a = satt + h * 32;
    float logit = 0.f;
    #pragma unroll
    for (int q = 0; q < 8; q++) {
        float4 l = pl[q], r = pr[q];
        float s;
        s = l.x + r.x; s = s > 0.f ? s : 0.2f * s; logit += s * a[q*4+0];
        s = l.y + r.y; s = s > 0.f ? s : 0.2f * s; logit += s * a[q*4+1];
        s = l.z + r.z; s = s > 0.f ? s : 0.2f * s; logit += s * a[q*4+2];
        s = l.w + r.w; s = s > 0.f ? s : 0.2f * s; logit += s * a[q*4+3];
    }
    float ex = __expf(logit);
    expl[(size_t)e * 4 + h] = ex;
    atomicAdd(&denom[(size_t)dst * 4 + h], ex);
}

// ---------------- layer-1 aggregation: one thread per (edge, channel)
__global__ __launch_bounds__(256) void agg1(
    const int* __restrict__ ei, const float* __restrict__ xl,
    const float* __restrict__ expl, const float* __restrict__ denom, float* __restrict__ h1)
{
    int t = blockIdx.x * 256 + threadIdx.x;
    // NEP*128 = 217,600,000 < 2^31
    if (t >= NEP * 128) return;
    int e = t >> 7, ch = t & 127;
    int src, dst;
    if (e < NE) { src = ei[e]; dst = ei[NE + e]; } else { src = dst = e - NE; }
    int hh = ch >> 5;
    float alpha = expl[(size_t)e * 4 + hh] / (denom[(size_t)dst * 4 + hh] + 1e-16f);
    atomicAdd(&h1[(size_t)dst * 128 + ch], xl[(size_t)src * 128 + ch] * alpha);
}

// ---------------- bias + BN + ELU (in place), CH channels
template<int CH>
__global__ __launch_bounds__(256) void post_bn_elu(
    float* __restrict__ h, const float* __restrict__ bias,
    const float* __restrict__ g, const float* __restrict__ b,
    const float* __restrict__ m, const float* __restrict__ v)
{
    int t = blockIdx.x * 256 + threadIdx.x;
    if (t >= NN * CH) return;
    int ch = t & (CH - 1);
    float s = g[ch] * rsqrtf(v[ch] + 1e-5f);
    float sh = b[ch] - m[ch] * s;
    float x = h[t] + bias[ch];
    x = x * s + sh;
    h[t] = elu_f(x);
}

// ---------------- layer-2 edge logits: one thread per edge
__global__ __launch_bounds__(256) void edge2(
    const int* __restrict__ ei, const float* __restrict__ xl, const float* __restrict__ xr,
    const float* __restrict__ att, float* __restrict__ expl, float* __restrict__ denom)
{
    __shared__ float satt[32];
    int tid = threadIdx.x;
    if (tid < 32) satt[tid] = att[tid];
    __syncthreads();
    int e = blockIdx.x * 256 + tid;
    if (e >= NEP) return;
    int src, dst;
    if (e < NE) { src = ei[e]; dst = ei[NE + e]; } else { src = dst = e - NE; }
    const float4* pl = (const float4*)(xl + (size_t)src * 32);
    const float4* pr = (const float4*)(xr + (size_t)dst * 32);
    float logit = 0.f;
    #pragma unroll
    for (int q = 0; q < 8; q++) {
        float4 l = pl[q], r = pr[q];
        float s;
        s = l.x + r.x; s = s > 0.f ? s : 0.2f * s; logit += s * satt[q*4+0];
        s = l.y + r.y; s = s > 0.f ? s : 0.2f * s; logit += s * satt[q*4+1];
        s = l.z + r.z; s = s > 0.f ? s : 0.2f * s; logit += s * satt[q*4+2];
        s = l.w + r.w; s = s > 0.f ? s : 0.2f * s; logit += s * satt[q*4+3];
    }
    float ex = __expf(logit);
    expl[e] = ex;
    atomicAdd(&denom[dst], ex);
}

// ---------------- layer-2 aggregation: one thread per (edge, channel)
__global__ __launch_bounds__(256) void agg2(
    const int* __restrict__ ei, const float* __restrict__ xl,
    const float* __restrict__ expl, const float* __restrict__ denom, float* __restrict__ h2)
{
    int t = blockIdx.x * 256 + threadIdx.x;
    if (t >= NEP * 32) return;
    int e = t >> 5, ch = t & 31;
    int src, dst;
    if (e < NE) { src = ei[e]; dst = ei[NE + e]; } else { src = dst = e - NE; }
    float alpha = expl[e] / (denom[dst] + 1e-16f);
    atomicAdd(&h2[(size_t)dst * 32 + ch], xl[(size_t)src * 32 + ch] * alpha);
}

// ---------------- prediction head: Linear(32,50)
__global__ __launch_bounds__(256) void predk(
    const float* __restrict__ h, const float* __restrict__ W,
    const float* __restrict__ bias, float* __restrict__ out)
{
    __shared__ float sW[50 * 32];
    __shared__ float sb[50];
    int tid = threadIdx.x;
    for (int idx = tid; idx < 1600; idx += 256) sW[idx] = W[idx];
    if (tid < 50) sb[tid] = bias[tid];
    __syncthreads();
    int t = blockIdx.x * 256 + tid;
    if (t >= NN * 50) return;
    int i = t / 50, j = t - i * 50;
    const float* hr = h + (size_t)i * 32;
    float acc = sb[j];
    #pragma unroll
    for (int k = 0; k < 32; k++) acc += hr[k] * sW[j * 32 + k];
    out[t] = acc;
}

extern "C" void kernel_launch(void* const* d_in, const int* in_sizes, int n_in,
                              void* d_out, int out_size, void* d_ws, size_t ws_size,
                              hipStream_t stream)
{
    const float* x_pca = (const float*)d_in[0];
    const float* x_bio = (const float*)d_in[1];
    const int*   ei    = (const int*)d_in[2];
    const float* bioW1 = (const float*)d_in[3];
    const float* biob1 = (const float*)d_in[4];
    const float* bn0_g = (const float*)d_in[5];
    const float* bn0_b = (const float*)d_in[6];
    const float* bn0_m = (const float*)d_in[7];
    const float* bn0_v = (const float*)d_in[8];
    const float* bioW2 = (const float*)d_in[9];
    const float* biob2 = (const float*)d_in[10];
    const float* Wl1   = (const float*)d_in[11];
    const float* bl1   = (const float*)d_in[12];
    const float* Wr1   = (const float*)d_in[13];
    const float* br1   = (const float*)d_in[14];
    const float* att1  = (const float*)d_in[15];
    const float* bias1 = (const float*)d_in[16];
    const float* bn1_g = (const float*)d_in[17];
    const float* bn1_b = (const float*)d_in[18];
    const float* bn1_m = (const float*)d_in[19];
    const float* bn1_v = (const float*)d_in[20];
    const float* Wl2   = (const float*)d_in[21];
    const float* bl2   = (const float*)d_in[22];
    const float* Wr2   = (const float*)d_in[23];
    const float* br2   = (const float*)d_in[24];
    const float* att2  = (const float*)d_in[25];
    const float* bias2 = (const float*)d_in[26];
    const float* bn2_g = (const float*)d_in[27];
    const float* bn2_b = (const float*)d_in[28];
    const float* bn2_m = (const float*)d_in[29];
    const float* bn2_v = (const float*)d_in[30];
    const float* predW = (const float*)d_in[31];
    const float* predb = (const float*)d_in[32];

    float* ws = (float*)d_ws;
    float* x      = ws;                       // N*66   = 6,600,000
    float* xl1    = x      + 6600000;         // N*128  = 12,800,000
    float* xr1    = xl1    + 12800000;        // N*128  = 12,800,000
    float* expl1  = xr1    + 12800000;        // NEP*4  = 6,800,000
    float* denom1 = expl1  + 6800000;         // N*4    = 400,000
    float* h1     = denom1 + 400000;          // N*128  = 12,800,000
    // layer-2 reuse (after layer-1 consumers are done):
    float* xl2    = x;                        // N*32
    float* xr2    = x + 3200000;              // N*32
    float* expl2  = xl1;                      // NEP
    float* denom2 = denom1;                   // N
    float* h2     = xr1;                      // N*32

    float* out = (float*)d_out;

    // zero accumulators for layer 1
    hipMemsetAsync(denom1, 0, (size_t)NN * 4 * sizeof(float), stream);
    hipMemsetAsync(h1, 0, (size_t)NN * 128 * sizeof(float), stream);

    // node features
    bio_kernel<<<(NN + 255) / 256, 256, 0, stream>>>(
        x_bio, bioW1, biob1, bn0_g, bn0_b, bn0_m, bn0_v, bioW2, biob2, x);
    copy_pca<<<(NN * 50 + 255) / 256, 256, 0, stream>>>(x_pca, x);

    // layer-1 transforms
    gemm_rowtile<66, 128, 16><<<(NN + 15) / 16, 256, 0, stream>>>(x, Wl1, bl1, xl1, NN);
    gemm_rowtile<66, 128, 16><<<(NN + 15) / 16, 256, 0, stream>>>(x, Wr1, br1, xr1, NN);

    // layer-1 edge phase
    edge1<<<(NEP * 4 + 255) / 256, 256, 0, stream>>>(ei, xl1, xr1, att1, expl1, denom1);
    agg1<<<(NEP * 128 + 255) / 256, 256, 0, stream>>>(ei, xl1, expl1, denom1, h1);
    post_bn_elu<128><<<(NN * 128 + 255) / 256, 256, 0, stream>>>(
        h1, bias1, bn1_g, bn1_b, bn1_m, bn1_v);

    // layer-2 transforms (input h1); xl2/xr2 overwrite x (done), h2 overwrites xr1 (done)
    gemm_rowtile<128, 32, 16><<<(NN + 15) / 16, 256, 0, stream>>>(h1, Wl2, bl2, xl2, NN);
    gemm_rowtile<128, 32, 16><<<(NN + 15) / 16, 256, 0, stream>>>(h1, Wr2, br2, xr2, NN);

    // zero accumulators for layer 2 (after their regions' previous users are done)
    hipMemsetAsync(denom2, 0, (size_t)NN * sizeof(float), stream);
    hipMemsetAsync(h2, 0, (size_t)NN * 32 * sizeof(float), stream);

    // layer-2 edge phase
    edge2<<<(NEP + 255) / 256, 256, 0, stream>>>(ei, xl2, xr2, att2, expl2, denom2);
    agg2<<<(NEP * 32 + 255) / 256, 256, 0, stream>>>(ei, xl2, expl2, denom2, h2);
    post_bn_elu<32><<<(NN * 32 + 255) / 256, 256, 0, stream>>>(
        h2, bias2, bn2_g, bn2_b, bn2_m, bn2_v);

    // prediction head
    predk<<<(NN * 50 + 255) / 256, 256, 0, stream>>>(h2, predW, predb, out);
}

// Round 2
// 1311.823 us; speedup vs baseline: 1.5042x; 1.5042x over previous
//
#include <hip/hip_runtime.h>
#include <cstdint>
#include <cstddef>

#define NN 100000
#define NE 1600000
#define NEP (NE + NN)   // edges + self-loops = 1,700,000

__device__ __forceinline__ float elu_f(float x) {
    return x > 0.f ? x : __expf(x) - 1.f;
}

// ================= CSR build (counting sort by dst) =================

__global__ __launch_bounds__(256) void count_deg(const int* __restrict__ ei, int* __restrict__ deg)
{
    int e = blockIdx.x * 256 + threadIdx.x;
    if (e >= NEP) return;
    int dst = (e < NE) ? ei[NE + e] : e - NE;
    atomicAdd(&deg[dst], 1);
}

// single block; deg[] becomes the running cursor (== offsets), off[] = offsets with off[NN]=NEP
__global__ __launch_bounds__(256) void scan_deg(int* __restrict__ deg, int* __restrict__ off)
{
    __shared__ int part[256];
    const int CH = (NN + 255) / 256;   // 391
    int t = threadIdx.x;
    int st = t * CH;
    int s = 0;
    for (int i = 0; i < CH; i++) { int j = st + i; if (j < NN) s += deg[j]; }
    part[t] = s;
    __syncthreads();
    if (t == 0) {
        int run = 0;
        for (int i = 0; i < 256; i++) { int v = part[i]; part[i] = run; run += v; }
    }
    __syncthreads();
    int run = part[t];
    for (int i = 0; i < CH; i++) {
        int j = st + i;
        if (j < NN) {
            int d = deg[j];
            off[j] = run;
            deg[j] = run;   // cursor for scatter
            run += d;
        }
    }
    if (t == 255) off[NN] = run;  // thread 255's chunk covers the tail
}

__global__ __launch_bounds__(256) void scatter_csr(const int* __restrict__ ei,
                                                   int* __restrict__ cursor, int* __restrict__ csr)
{
    int e = blockIdx.x * 256 + threadIdx.x;
    if (e >= NEP) return;
    int src, dst;
    if (e < NE) { src = ei[e]; dst = ei[NE + e]; } else { src = dst = e - NE; }
    int pos = atomicAdd(&cursor[dst], 1);
    csr[pos] = src;
}

// ================= node feature prep =================

__global__ __launch_bounds__(256) void bio_kernel(
    const float* __restrict__ xb, const float* __restrict__ W1, const float* __restrict__ b1,
    const float* __restrict__ g0, const float* __restrict__ bb0,
    const float* __restrict__ m0, const float* __restrict__ v0,
    const float* __restrict__ W2, const float* __restrict__ b2,
    float* __restrict__ x)
{
    __shared__ float sW1[16*64], sW2[16*16], sb1[16], sb2[16], ss[16], st[16];
    int tid = threadIdx.x;
    for (int idx = tid; idx < 1024; idx += 256) sW1[idx] = W1[idx];
    if (tid < 256) sW2[tid] = W2[tid];
    if (tid < 16) {
        sb1[tid] = b1[tid]; sb2[tid] = b2[tid];
        float s = g0[tid] * rsqrtf(v0[tid] + 1e-5f);
        ss[tid] = s; st[tid] = bb0[tid] - m0[tid] * s;
    }
    __syncthreads();
    int i = blockIdx.x * 256 + tid;
    if (i >= NN) return;
    float bio[64];
    const float4* p = (const float4*)(xb + (size_t)i * 64);
    #pragma unroll
    for (int q = 0; q < 16; q++) {
        float4 f = p[q];
        bio[q*4] = f.x; bio[q*4+1] = f.y; bio[q*4+2] = f.z; bio[q*4+3] = f.w;
    }
    float t1[16];
    #pragma unroll
    for (int j = 0; j < 16; j++) {
        float acc = sb1[j];
        #pragma unroll
        for (int k = 0; k < 64; k++) acc += bio[k] * sW1[j*64 + k];
        acc = acc * ss[j] + st[j];
        t1[j] = elu_f(acc);
    }
    float* xo = x + (size_t)i * 66 + 50;
    #pragma unroll
    for (int j = 0; j < 16; j++) {
        float acc = sb2[j];
        #pragma unroll
        for (int k = 0; k < 16; k++) acc += t1[k] * sW2[j*16 + k];
        xo[j] = elu_f(acc);
    }
}

__global__ __launch_bounds__(256) void copy_pca(const float* __restrict__ xp, float* __restrict__ x)
{
    int t = blockIdx.x * 256 + threadIdx.x;
    if (t >= NN * 50) return;
    int i = t / 50, j = t - i * 50;
    x[(size_t)i * 66 + j] = xp[t];
}

// ================= row-tiled GEMM: out[n,DOUT] = in @ W^T + b =================

template<int DIN, int DOUT, int NPB>
__global__ __launch_bounds__(256) void gemm_rowtile(
    const float* __restrict__ in, const float* __restrict__ W,
    const float* __restrict__ bias, float* __restrict__ out, int n)
{
    constexpr int GROUPS = 256 / DOUT;
    constexpr int RPT = NPB / GROUPS;
    __shared__ float sW[DOUT * DIN];
    __shared__ float sx[NPB * DIN];
    __shared__ float sb[DOUT];
    int tid = threadIdx.x;
    for (int idx = tid; idx < DOUT * DIN; idx += 256) sW[idx] = W[idx];
    if (tid < DOUT) sb[tid] = bias[tid];
    int node0 = blockIdx.x * NPB;
    for (int idx = tid; idx < NPB * DIN; idx += 256) {
        int r = idx / DIN, c = idx - r * DIN;
        int i = node0 + r;
        sx[idx] = (i < n) ? in[(size_t)i * DIN + c] : 0.f;
    }
    __syncthreads();
    int j = tid % DOUT;
    int g = tid / DOUT;
    float acc[RPT];
    #pragma unroll
    for (int r = 0; r < RPT; r++) acc[r] = sb[j];
    for (int k = 0; k < DIN; k++) {
        float w = sW[j * DIN + k];
        #pragma unroll
        for (int r = 0; r < RPT; r++) acc[r] += sx[(g * RPT + r) * DIN + k] * w;
    }
    #pragma unroll
    for (int r = 0; r < RPT; r++) {
        int i = node0 + g * RPT + r;
        if (i < n) out[(size_t)i * DOUT + j] = acc[r];
    }
}

// ================= fused GATv2 layer 1: one wave per dst node =================
// 128 channels, 4 heads. lane l handles channels {2l, 2l+1} (same head: (2l)>>5 == l>>4).
// Head-group = 16 consecutive lanes; butterfly reduce with xor masks 1,2,4,8.
__global__ __launch_bounds__(256) void fused_gat1(
    const int* __restrict__ off, const int* __restrict__ csr,
    const float* __restrict__ xl, const float* __restrict__ xr,
    const float* __restrict__ att, const float* __restrict__ bias,
    const float* __restrict__ g, const float* __restrict__ b,
    const float* __restrict__ m, const float* __restrict__ v,
    float* __restrict__ h1)
{
    int wave = threadIdx.x >> 6;
    int lane = threadIdx.x & 63;
    int node = blockIdx.x * 4 + wave;
    if (node >= NN) return;
    int ch = lane * 2;

    float2 xrv = *(const float2*)(xr + (size_t)node * 128 + ch);
    float2 av  = *(const float2*)(att + ch);

    int k0 = off[node], k1 = off[node + 1];
    float accx = 0.f, accy = 0.f, denom = 0.f;

    for (int base = k0; base < k1; base += 64) {
        int nb = min(64, k1 - base);
        int mysrc = (lane < nb) ? csr[base + lane] : 0;
        for (int t = 0; t < nb; t++) {
            int src = __shfl(mysrc, t, 64);
            float2 xlv = *(const float2*)(xl + (size_t)src * 128 + ch);
            float sx = xlv.x + xrv.x; sx = sx > 0.f ? sx : 0.2f * sx;
            float sy = xlv.y + xrv.y; sy = sy > 0.f ? sy : 0.2f * sy;
            float p = sx * av.x + sy * av.y;
            p += __shfl_xor(p, 1, 64);
            p += __shfl_xor(p, 2, 64);
            p += __shfl_xor(p, 4, 64);
            p += __shfl_xor(p, 8, 64);
            float w = __expf(p);
            denom += w;
            accx += xlv.x * w;
            accy += xlv.y * w;
        }
    }
    float inv = 1.f / (denom + 1e-16f);
    // epilogue: + bias1, BN, ELU
    float sX = g[ch]     * rsqrtf(v[ch]     + 1e-5f);
    float sY = g[ch + 1] * rsqrtf(v[ch + 1] + 1e-5f);
    float ox = accx * inv + bias[ch];
    float oy = accy * inv + bias[ch + 1];
    ox = ox * sX + (b[ch]     - m[ch]     * sX);
    oy = oy * sY + (b[ch + 1] - m[ch + 1] * sY);
    float2 o; o.x = elu_f(ox); o.y = elu_f(oy);
    *(float2*)(h1 + (size_t)node * 128 + ch) = o;
}

// ================= fused GATv2 layer 2: one wave per dst node =================
// 32 channels, 1 head; 2 edges per iteration (lane = slot*32 + c).
__global__ __launch_bounds__(256) void fused_gat2(
    const int* __restrict__ off, const int* __restrict__ csr,
    const float* __restrict__ xl, const float* __restrict__ xr,
    const float* __restrict__ att, const float* __restrict__ bias,
    const float* __restrict__ g, const float* __restrict__ b,
    const float* __restrict__ m, const float* __restrict__ v,
    float* __restrict__ h2)
{
    int wave = threadIdx.x >> 6;
    int lane = threadIdx.x & 63;
    int node = blockIdx.x * 4 + wave;
    if (node >= NN) return;
    int slot = lane >> 5;      // 0 or 1
    int c = lane & 31;

    float xrv = xr[(size_t)node * 32 + c];
    float attv = att[c];

    int k0 = off[node], k1 = off[node + 1];
    float acc = 0.f, denom = 0.f;

    for (int base = k0; base < k1; base += 64) {
        int nb = min(64, k1 - base);
        int mysrc = (lane < nb) ? csr[base + lane] : 0;
        for (int t = 0; t < nb; t += 2) {
            int idx = t + slot;
            bool valid = idx < nb;
            int src = __shfl(mysrc, valid ? idx : 0, 64);
            float xlv = xl[(size_t)src * 32 + c];
            float s = xlv + xrv; s = s > 0.f ? s : 0.2f * s;
            float p = s * attv;
            p += __shfl_xor(p, 1, 64);
            p += __shfl_xor(p, 2, 64);
            p += __shfl_xor(p, 4, 64);
            p += __shfl_xor(p, 8, 64);
            p += __shfl_xor(p, 16, 64);
            float w = valid ? __expf(p) : 0.f;
            denom += w;
            acc += xlv * w;
        }
    }
    // combine the two edge slots
    acc   += __shfl_xor(acc, 32, 64);
    denom += __shfl_xor(denom, 32, 64);
    if (slot == 0) {
        float inv = 1.f / (denom + 1e-16f);
        float sC = g[c] * rsqrtf(v[c] + 1e-5f);
        float o = acc * inv + bias[c];
        o = o * sC + (b[c] - m[c] * sC);
        h2[(size_t)node * 32 + c] = elu_f(o);
    }
}

// ================= prediction head: Linear(32,50) =================

__global__ __launch_bounds__(256) void predk(
    const float* __restrict__ h, const float* __restrict__ W,
    const float* __restrict__ bias, float* __restrict__ out)
{
    __shared__ float sW[50 * 32];
    __shared__ float sb[50];
    int tid = threadIdx.x;
    for (int idx = tid; idx < 1600; idx += 256) sW[idx] = W[idx];
    if (tid < 50) sb[tid] = bias[tid];
    __syncthreads();
    int t = blockIdx.x * 256 + tid;
    if (t >= NN * 50) return;
    int i = t / 50, j = t - i * 50;
    const float* hr = h + (size_t)i * 32;
    float acc = sb[j];
    #pragma unroll
    for (int k = 0; k < 32; k++) acc += hr[k] * sW[j * 32 + k];
    out[t] = acc;
}

extern "C" void kernel_launch(void* const* d_in, const int* in_sizes, int n_in,
                              void* d_out, int out_size, void* d_ws, size_t ws_size,
                              hipStream_t stream)
{
    const float* x_pca = (const float*)d_in[0];
    const float* x_bio = (const float*)d_in[1];
    const int*   ei    = (const int*)d_in[2];
    const float* bioW1 = (const float*)d_in[3];
    const float* biob1 = (const float*)d_in[4];
    const float* bn0_g = (const float*)d_in[5];
    const float* bn0_b = (const float*)d_in[6];
    const float* bn0_m = (const float*)d_in[7];
    const float* bn0_v = (const float*)d_in[8];
    const float* bioW2 = (const float*)d_in[9];
    const float* biob2 = (const float*)d_in[10];
    const float* Wl1   = (const float*)d_in[11];
    const float* bl1   = (const float*)d_in[12];
    const float* Wr1   = (const float*)d_in[13];
    const float* br1   = (const float*)d_in[14];
    const float* att1  = (const float*)d_in[15];
    const float* bias1 = (const float*)d_in[16];
    const float* bn1_g = (const float*)d_in[17];
    const float* bn1_b = (const float*)d_in[18];
    const float* bn1_m = (const float*)d_in[19];
    const float* bn1_v = (const float*)d_in[20];
    const float* Wl2   = (const float*)d_in[21];
    const float* bl2   = (const float*)d_in[22];
    const float* Wr2   = (const float*)d_in[23];
    const float* br2   = (const float*)d_in[24];
    const float* att2  = (const float*)d_in[25];
    const float* bias2 = (const float*)d_in[26];
    const float* bn2_g = (const float*)d_in[27];
    const float* bn2_b = (const float*)d_in[28];
    const float* bn2_m = (const float*)d_in[29];
    const float* bn2_v = (const float*)d_in[30];
    const float* predW = (const float*)d_in[31];
    const float* predb = (const float*)d_in[32];

    float* ws = (float*)d_ws;
    float* x    = ws;                 // N*66   = 6,600,000 floats
    float* xl1  = x   + 6600000;      // N*128  = 12,800,000
    float* xr1  = xl1 + 12800000;     // N*128  = 12,800,000
    float* h1   = xr1 + 12800000;     // N*128  = 12,800,000
    int*   ibase = (int*)(h1 + 12800000);
    int*   degcur = ibase;            // NN      (degree, then cursor)
    int*   off    = ibase + NN;       // NN+1
    int*   csr    = off + NN + 1;     // NEP = 1,700,000
    // layer-2 buffer reuse:
    float* xl2 = x;                   // N*32 (x done after layer-1 gemms)
    float* xr2 = x + 3200000;         // N*32
    float* h2  = xr1;                 // N*32 (xr1 done after fused_gat1)

    float* out = (float*)d_out;

    // ---- CSR build (depends only on edge_index; deterministic content) ----
    hipMemsetAsync(degcur, 0, (size_t)NN * sizeof(int), stream);
    count_deg<<<(NEP + 255) / 256, 256, 0, stream>>>(ei, degcur);
    scan_deg<<<1, 256, 0, stream>>>(degcur, off);
    scatter_csr<<<(NEP + 255) / 256, 256, 0, stream>>>(ei, degcur, csr);

    // ---- node features ----
    bio_kernel<<<(NN + 255) / 256, 256, 0, stream>>>(
        x_bio, bioW1, biob1, bn0_g, bn0_b, bn0_m, bn0_v, bioW2, biob2, x);
    copy_pca<<<(NN * 50 + 255) / 256, 256, 0, stream>>>(x_pca, x);

    // ---- layer-1 transforms ----
    gemm_rowtile<66, 128, 16><<<(NN + 15) / 16, 256, 0, stream>>>(x, Wl1, bl1, xl1, NN);
    gemm_rowtile<66, 128, 16><<<(NN + 15) / 16, 256, 0, stream>>>(x, Wr1, br1, xr1, NN);

    // ---- fused layer-1 edge phase + bias/BN/ELU ----
    fused_gat1<<<(NN + 3) / 4, 256, 0, stream>>>(
        off, csr, xl1, xr1, att1, bias1, bn1_g, bn1_b, bn1_m, bn1_v, h1);

    // ---- layer-2 transforms (xl2/xr2 overwrite x) ----
    gemm_rowtile<128, 32, 16><<<(NN + 15) / 16, 256, 0, stream>>>(h1, Wl2, bl2, xl2, NN);
    gemm_rowtile<128, 32, 16><<<(NN + 15) / 16, 256, 0, stream>>>(h1, Wr2, br2, xr2, NN);

    // ---- fused layer-2 edge phase + bias/BN/ELU (h2 overwrites xr1) ----
    fused_gat2<<<(NN + 3) / 4, 256, 0, stream>>>(
        off, csr, xl2, xr2, att2, bias2, bn2_g, bn2_b, bn2_m, bn2_v, h2);

    // ---- prediction head ----
    predk<<<(NN * 50 + 255) / 256, 256, 0, stream>>>(h2, predW, predb, out);
}

// Round 3
// 1039.152 us; speedup vs baseline: 1.8989x; 1.2624x over previous
//
#include <hip/hip_runtime.h>
#include <cstdint>
#include <cstddef>

#define NN 100000
#define NE 1600000
#define NEP (NE + NN)   // edges + self-loops = 1,700,000
#define SCAN_BLOCKS ((NN + 1023) / 1024)   // 98

__device__ __forceinline__ float elu_f(float x) {
    return x > 0.f ? x : __expf(x) - 1.f;
}

// ================= CSR build (counting sort by dst) =================

__global__ __launch_bounds__(256) void count_deg(const int* __restrict__ ei, int* __restrict__ deg)
{
    int e = blockIdx.x * 256 + threadIdx.x;
    if (e >= NEP) return;
    int dst = (e < NE) ? ei[NE + e] : e - NE;
    atomicAdd(&deg[dst], 1);
}

// pass 1: per-1024-chunk sums -> part[98]
__global__ __launch_bounds__(256) void scan_pass1(const int* __restrict__ deg, int* __restrict__ part)
{
    __shared__ int wsum[4];
    int t = threadIdx.x;
    int i0 = blockIdx.x * 1024 + t * 4;
    int s = 0;
    if (i0 + 3 < NN) { int4 d = *(const int4*)(deg + i0); s = d.x + d.y + d.z + d.w; }
    else {
        for (int k = 0; k < 4; k++) if (i0 + k < NN) s += deg[i0 + k];
    }
    for (int d = 1; d < 64; d <<= 1) s += __shfl_xor(s, d, 64);
    if ((t & 63) == 0) wsum[t >> 6] = s;
    __syncthreads();
    if (t == 0) part[blockIdx.x] = wsum[0] + wsum[1] + wsum[2] + wsum[3];
}

// pass 2: exclusive scan of the 98 partials in place; writes off[NN] (= NEP)
__global__ __launch_bounds__(128) void scan_pass2(int* __restrict__ part, int* __restrict__ off)
{
    __shared__ int wt[2];
    int t = threadIdx.x;            // 128 threads
    int lane = t & 63, w = t >> 6;
    int v = (t < SCAN_BLOCKS) ? part[t] : 0;
    int x = v;
    for (int d = 1; d < 64; d <<= 1) { int y = __shfl_up(x, d, 64); if (lane >= d) x += y; }
    if (lane == 63) wt[w] = x;
    __syncthreads();
    int base = (w == 1) ? wt[0] : 0;
    int excl = base + x - v;
    if (t < SCAN_BLOCKS) part[t] = excl;
    if (t == SCAN_BLOCKS - 1) off[NN] = excl + v;
}

// pass 3: full exclusive scan -> off[] and cursor[]
__global__ __launch_bounds__(256) void scan_pass3(const int* __restrict__ deg, const int* __restrict__ part,
                                                  int* __restrict__ off, int* __restrict__ cursor)
{
    __shared__ int wsum[4];
    int t = threadIdx.x, lane = t & 63, w = t >> 6;
    int i0 = blockIdx.x * 1024 + t * 4;
    int d0 = 0, d1 = 0, d2 = 0, d3 = 0;
    if (i0 + 3 < NN) { int4 d = *(const int4*)(deg + i0); d0 = d.x; d1 = d.y; d2 = d.z; d3 = d.w; }
    else if (i0 < NN) {
        d0 = deg[i0];
        if (i0 + 1 < NN) d1 = deg[i0 + 1];
        if (i0 + 2 < NN) d2 = deg[i0 + 2];
    }
    int s = d0 + d1 + d2 + d3;
    int x = s;
    for (int d = 1; d < 64; d <<= 1) { int y = __shfl_up(x, d, 64); if (lane >= d) x += y; }
    if (lane == 63) wsum[w] = x;
    __syncthreads();
    int wbase = 0;
    for (int i = 0; i < w; i++) wbase += wsum[i];
    int base = part[blockIdx.x] + wbase + x - s;
    if (i0 < NN)     { off[i0]     = base;                cursor[i0]     = base; }
    if (i0 + 1 < NN) { off[i0 + 1] = base + d0;           cursor[i0 + 1] = base + d0; }
    if (i0 + 2 < NN) { off[i0 + 2] = base + d0 + d1;      cursor[i0 + 2] = base + d0 + d1; }
    if (i0 + 3 < NN) { off[i0 + 3] = base + d0 + d1 + d2; cursor[i0 + 3] = base + d0 + d1 + d2; }
}

__global__ __launch_bounds__(256) void scatter_csr(const int* __restrict__ ei,
                                                   int* __restrict__ cursor, int* __restrict__ csr)
{
    int e = blockIdx.x * 256 + threadIdx.x;
    if (e >= NEP) return;
    int src, dst;
    if (e < NE) { src = ei[e]; dst = ei[NE + e]; } else { src = dst = e - NE; }
    int pos = atomicAdd(&cursor[dst], 1);
    csr[pos] = src;
}

// ================= node feature prep =================

__global__ __launch_bounds__(256) void bio_kernel(
    const float* __restrict__ xb, const float* __restrict__ W1, const float* __restrict__ b1,
    const float* __restrict__ g0, const float* __restrict__ bb0,
    const float* __restrict__ m0, const float* __restrict__ v0,
    const float* __restrict__ W2, const float* __restrict__ b2,
    float* __restrict__ x)
{
    __shared__ float sW1[16*64], sW2[16*16], sb1[16], sb2[16], ss[16], st[16];
    int tid = threadIdx.x;
    for (int idx = tid; idx < 1024; idx += 256) sW1[idx] = W1[idx];
    if (tid < 256) sW2[tid] = W2[tid];
    if (tid < 16) {
        sb1[tid] = b1[tid]; sb2[tid] = b2[tid];
        float s = g0[tid] * rsqrtf(v0[tid] + 1e-5f);
        ss[tid] = s; st[tid] = bb0[tid] - m0[tid] * s;
    }
    __syncthreads();
    int i = blockIdx.x * 256 + tid;
    if (i >= NN) return;
    float bio[64];
    const float4* p = (const float4*)(xb + (size_t)i * 64);
    #pragma unroll
    for (int q = 0; q < 16; q++) {
        float4 f = p[q];
        bio[q*4] = f.x; bio[q*4+1] = f.y; bio[q*4+2] = f.z; bio[q*4+3] = f.w;
    }
    float t1[16];
    #pragma unroll
    for (int j = 0; j < 16; j++) {
        float acc = sb1[j];
        #pragma unroll
        for (int k = 0; k < 64; k++) acc += bio[k] * sW1[j*64 + k];
        acc = acc * ss[j] + st[j];
        t1[j] = elu_f(acc);
    }
    float* xo = x + (size_t)i * 66 + 50;
    #pragma unroll
    for (int j = 0; j < 16; j++) {
        float acc = sb2[j];
        #pragma unroll
        for (int k = 0; k < 16; k++) acc += t1[k] * sW2[j*16 + k];
        xo[j] = elu_f(acc);
    }
}

__global__ __launch_bounds__(256) void copy_pca(const float* __restrict__ xp, float* __restrict__ x)
{
    int t = blockIdx.x * 256 + threadIdx.x;
    if (t >= NN * 50) return;
    int i = t / 50, j = t - i * 50;
    x[(size_t)i * 66 + j] = xp[t];
}

// ================= row-tiled GEMM: out[n,DOUT] = in @ W^T + b =================

template<int DIN, int DOUT, int NPB>
__global__ __launch_bounds__(256) void gemm_rowtile(
    const float* __restrict__ in, const float* __restrict__ W,
    const float* __restrict__ bias, float* __restrict__ out, int n)
{
    constexpr int GROUPS = 256 / DOUT;
    constexpr int RPT = NPB / GROUPS;
    __shared__ float sW[DOUT * DIN];
    __shared__ float sx[NPB * DIN];
    __shared__ float sb[DOUT];
    int tid = threadIdx.x;
    for (int idx = tid; idx < DOUT * DIN; idx += 256) sW[idx] = W[idx];
    if (tid < DOUT) sb[tid] = bias[tid];
    int node0 = blockIdx.x * NPB;
    for (int idx = tid; idx < NPB * DIN; idx += 256) {
        int r = idx / DIN, c = idx - r * DIN;
        int i = node0 + r;
        sx[idx] = (i < n) ? in[(size_t)i * DIN + c] : 0.f;
    }
    __syncthreads();
    int j = tid % DOUT;
    int g = tid / DOUT;
    float acc[RPT];
    #pragma unroll
    for (int r = 0; r < RPT; r++) acc[r] = sb[j];
    for (int k = 0; k < DIN; k++) {
        float w = sW[j * DIN + k];
        #pragma unroll
        for (int r = 0; r < RPT; r++) acc[r] += sx[(g * RPT + r) * DIN + k] * w;
    }
    #pragma unroll
    for (int r = 0; r < RPT; r++) {
        int i = node0 + g * RPT + r;
        if (i < n) out[(size_t)i * DOUT + j] = acc[r];
    }
}

// ================= fused GATv2 layer 1: one wave per dst node =================
__global__ __launch_bounds__(256) void fused_gat1(
    const int* __restrict__ off, const int* __restrict__ csr,
    const float* __restrict__ xl, const float* __restrict__ xr,
    const float* __restrict__ att, const float* __restrict__ bias,
    const float* __restrict__ g, const float* __restrict__ b,
    const float* __restrict__ m, const float* __restrict__ v,
    float* __restrict__ h1)
{
    int wave = threadIdx.x >> 6;
    int lane = threadIdx.x & 63;
    int node = blockIdx.x * 4 + wave;
    if (node >= NN) return;
    int ch = lane * 2;

    float2 xrv = *(const float2*)(xr + (size_t)node * 128 + ch);
    float2 av  = *(const float2*)(att + ch);

    int k0 = off[node], k1 = off[node + 1];
    float accx = 0.f, accy = 0.f, denom = 0.f;

    for (int base = k0; base < k1; base += 64) {
        int nb = min(64, k1 - base);
        int mysrc = (lane < nb) ? csr[base + lane] : 0;
        for (int t = 0; t < nb; t++) {
            int src = __shfl(mysrc, t, 64);
            float2 xlv = *(const float2*)(xl + (size_t)src * 128 + ch);
            float sx = xlv.x + xrv.x; sx = sx > 0.f ? sx : 0.2f * sx;
            float sy = xlv.y + xrv.y; sy = sy > 0.f ? sy : 0.2f * sy;
            float p = sx * av.x + sy * av.y;
            p += __shfl_xor(p, 1, 64);
            p += __shfl_xor(p, 2, 64);
            p += __shfl_xor(p, 4, 64);
            p += __shfl_xor(p, 8, 64);
            float w = __expf(p);
            denom += w;
            accx += xlv.x * w;
            accy += xlv.y * w;
        }
    }
    float inv = 1.f / (denom + 1e-16f);
    float sX = g[ch]     * rsqrtf(v[ch]     + 1e-5f);
    float sY = g[ch + 1] * rsqrtf(v[ch + 1] + 1e-5f);
    float ox = accx * inv + bias[ch];
    float oy = accy * inv + bias[ch + 1];
    ox = ox * sX + (b[ch]     - m[ch]     * sX);
    oy = oy * sY + (b[ch + 1] - m[ch + 1] * sY);
    float2 o; o.x = elu_f(ox); o.y = elu_f(oy);
    *(float2*)(h1 + (size_t)node * 128 + ch) = o;
}

// ================= fused GATv2 layer 2: one wave per dst node =================
__global__ __launch_bounds__(256) void fused_gat2(
    const int* __restrict__ off, const int* __restrict__ csr,
    const float* __restrict__ xl, const float* __restrict__ xr,
    const float* __restrict__ att, const float* __restrict__ bias,
    const float* __restrict__ g, const float* __restrict__ b,
    const float* __restrict__ m, const float* __restrict__ v,
    float* __restrict__ h2)
{
    int wave = threadIdx.x >> 6;
    int lane = threadIdx.x & 63;
    int node = blockIdx.x * 4 + wave;
    if (node >= NN) return;
    int slot = lane >> 5;      // 0 or 1
    int c = lane & 31;

    float xrv = xr[(size_t)node * 32 + c];
    float attv = att[c];

    int k0 = off[node], k1 = off[node + 1];
    float acc = 0.f, denom = 0.f;

    for (int base = k0; base < k1; base += 64) {
        int nb = min(64, k1 - base);
        int mysrc = (lane < nb) ? csr[base + lane] : 0;
        for (int t = 0; t < nb; t += 2) {
            int idx = t + slot;
            bool valid = idx < nb;
            int src = __shfl(mysrc, valid ? idx : 0, 64);
            float xlv = xl[(size_t)src * 32 + c];
            float s = xlv + xrv; s = s > 0.f ? s : 0.2f * s;
            float p = s * attv;
            p += __shfl_xor(p, 1, 64);
            p += __shfl_xor(p, 2, 64);
            p += __shfl_xor(p, 4, 64);
            p += __shfl_xor(p, 8, 64);
            p += __shfl_xor(p, 16, 64);
            float w = valid ? __expf(p) : 0.f;
            denom += w;
            acc += xlv * w;
        }
    }
    acc   += __shfl_xor(acc, 32, 64);
    denom += __shfl_xor(denom, 32, 64);
    if (slot == 0) {
        float inv = 1.f / (denom + 1e-16f);
        float sC = g[c] * rsqrtf(v[c] + 1e-5f);
        float o = acc * inv + bias[c];
        o = o * sC + (b[c] - m[c] * sC);
        h2[(size_t)node * 32 + c] = elu_f(o);
    }
}

// ================= prediction head: Linear(32,50) =================

__global__ __launch_bounds__(256) void predk(
    const float* __restrict__ h, const float* __restrict__ W,
    const float* __restrict__ bias, float* __restrict__ out)
{
    __shared__ float sW[50 * 32];
    __shared__ float sb[50];
    int tid = threadIdx.x;
    for (int idx = tid; idx < 1600; idx += 256) sW[idx] = W[idx];
    if (tid < 50) sb[tid] = bias[tid];
    __syncthreads();
    int t = blockIdx.x * 256 + tid;
    if (t >= NN * 50) return;
    int i = t / 50, j = t - i * 50;
    const float* hr = h + (size_t)i * 32;
    float acc = sb[j];
    #pragma unroll
    for (int k = 0; k < 32; k++) acc += hr[k] * sW[j * 32 + k];
    out[t] = acc;
}

extern "C" void kernel_launch(void* const* d_in, const int* in_sizes, int n_in,
                              void* d_out, int out_size, void* d_ws, size_t ws_size,
                              hipStream_t stream)
{
    const float* x_pca = (const float*)d_in[0];
    const float* x_bio = (const float*)d_in[1];
    const int*   ei    = (const int*)d_in[2];
    const float* bioW1 = (const float*)d_in[3];
    const float* biob1 = (const float*)d_in[4];
    const float* bn0_g = (const float*)d_in[5];
    const float* bn0_b = (const float*)d_in[6];
    const float* bn0_m = (const float*)d_in[7];
    const float* bn0_v = (const float*)d_in[8];
    const float* bioW2 = (const float*)d_in[9];
    const float* biob2 = (const float*)d_in[10];
    const float* Wl1   = (const float*)d_in[11];
    const float* bl1   = (const float*)d_in[12];
    const float* Wr1   = (const float*)d_in[13];
    const float* br1   = (const float*)d_in[14];
    const float* att1  = (const float*)d_in[15];
    const float* bias1 = (const float*)d_in[16];
    const float* bn1_g = (const float*)d_in[17];
    const float* bn1_b = (const float*)d_in[18];
    const float* bn1_m = (const float*)d_in[19];
    const float* bn1_v = (const float*)d_in[20];
    const float* Wl2   = (const float*)d_in[21];
    const float* bl2   = (const float*)d_in[22];
    const float* Wr2   = (const float*)d_in[23];
    const float* br2   = (const float*)d_in[24];
    const float* att2  = (const float*)d_in[25];
    const float* bias2 = (const float*)d_in[26];
    const float* bn2_g = (const float*)d_in[27];
    const float* bn2_b = (const float*)d_in[28];
    const float* bn2_m = (const float*)d_in[29];
    const float* bn2_v = (const float*)d_in[30];
    const float* predW = (const float*)d_in[31];
    const float* predb = (const float*)d_in[32];

    float* ws = (float*)d_ws;
    float* x    = ws;                 // N*66   = 6,600,000 floats
    float* xl1  = x   + 6600000;      // N*128  = 12,800,000
    float* xr1  = xl1 + 12800000;     // N*128  = 12,800,000
    float* h1   = xr1 + 12800000;     // N*128  = 12,800,000
    int*   ibase  = (int*)(h1 + 12800000);
    int*   deg    = ibase;            // NN
    int*   off    = ibase + NN;       // NN+1
    int*   cursor = off + NN + 1;     // NN
    int*   part   = cursor + NN;      // 128
    int*   csr    = part + 128;       // NEP = 1,700,000
    // layer-2 buffer reuse:
    float* xl2 = x;                   // N*32 (x done after layer-1 gemms)
    float* xr2 = x + 3200000;         // N*32
    float* h2  = xr1;                 // N*32 (xr1 done after fused_gat1)

    float* out = (float*)d_out;

    // ---- CSR build ----
    hipMemsetAsync(deg, 0, (size_t)NN * sizeof(int), stream);
    count_deg<<<(NEP + 255) / 256, 256, 0, stream>>>(ei, deg);
    scan_pass1<<<SCAN_BLOCKS, 256, 0, stream>>>(deg, part);
    scan_pass2<<<1, 128, 0, stream>>>(part, off);
    scan_pass3<<<SCAN_BLOCKS, 256, 0, stream>>>(deg, part, off, cursor);
    scatter_csr<<<(NEP + 255) / 256, 256, 0, stream>>>(ei, cursor, csr);

    // ---- node features ----
    bio_kernel<<<(NN + 255) / 256, 256, 0, stream>>>(
        x_bio, bioW1, biob1, bn0_g, bn0_b, bn0_m, bn0_v, bioW2, biob2, x);
    copy_pca<<<(NN * 50 + 255) / 256, 256, 0, stream>>>(x_pca, x);

    // ---- layer-1 transforms ----
    gemm_rowtile<66, 128, 16><<<(NN + 15) / 16, 256, 0, stream>>>(x, Wl1, bl1, xl1, NN);
    gemm_rowtile<66, 128, 16><<<(NN + 15) / 16, 256, 0, stream>>>(x, Wr1, br1, xr1, NN);

    // ---- fused layer-1 edge phase + bias/BN/ELU ----
    fused_gat1<<<(NN + 3) / 4, 256, 0, stream>>>(
        off, csr, xl1, xr1, att1, bias1, bn1_g, bn1_b, bn1_m, bn1_v, h1);

    // ---- layer-2 transforms (xl2/xr2 overwrite x) ----
    gemm_rowtile<128, 32, 16><<<(NN + 15) / 16, 256, 0, stream>>>(h1, Wl2, bl2, xl2, NN);
    gemm_rowtile<128, 32, 16><<<(NN + 15) / 16, 256, 0, stream>>>(h1, Wr2, br2, xr2, NN);

    // ---- fused layer-2 edge phase + bias/BN/ELU (h2 overwrites xr1) ----
    fused_gat2<<<(NN + 3) / 4, 256, 0, stream>>>(
        off, csr, xl2, xr2, att2, bias2, bn2_g, bn2_b, bn2_m, bn2_v, h2);

    // ---- prediction head ----
    predk<<<(NN * 50 + 255) / 256, 256, 0, stream>>>(h2, predW, predb, out);
}